// Round 1
// baseline (281.286 us; speedup 1.0000x reference)
//
#include <hip/hip_runtime.h>
#include <hip/hip_bf16.h>
#include <stdint.h>

typedef __attribute__((ext_vector_type(8))) short short8;
typedef __attribute__((ext_vector_type(4))) float float4v;
typedef __attribute__((ext_vector_type(4))) unsigned int uint4v;
typedef unsigned short u16;

#if __has_builtin(__builtin_amdgcn_exp2f)
#define EXP2F(x) __builtin_amdgcn_exp2f(x)
#else
#define EXP2F(x) __expf(0.69314718056f * (x))
#endif

__device__ __forceinline__ u16 f2b(float f) {
    union { __hip_bfloat16 b; u16 u; } cv;
    cv.b = __float2bfloat16(f);
    return cv.u;
}

#define GLD16(g, l) __builtin_amdgcn_global_load_lds( \
    (const __attribute__((address_space(1))) void*)(g), \
    (__attribute__((address_space(3))) void*)(l), 16, 0, 0)

// ---------------------------------------------------------------------------
// 1) Gather even rows of x (token t <- x row 2t) and convert fp32 -> bf16.
__global__ void convert_x(const float* __restrict__ x, u16* __restrict__ xb) {
    int id = blockIdx.x * 256 + threadIdx.x;
    int row = id >> 8;
    int c4 = id & 255;
    const float4* src = reinterpret_cast<const float4*>(x + (size_t)(2 * row) * 1024) + c4;
    float4 v = *src;
    ushort4 o;
    o.x = f2b(v.x); o.y = f2b(v.y); o.z = f2b(v.z); o.w = f2b(v.w);
    *(reinterpret_cast<ushort4*>(xb + (size_t)row * 1024) + c4) = o;
}

// ---------------------------------------------------------------------------
// 2) Transpose-convert: in fp32 [K][N] -> out bf16 [N][K].
__global__ void transpose_convert(const float* __restrict__ in, u16* __restrict__ out,
                                  int K, int N) {
    __shared__ float tile[32][33];
    int n0 = blockIdx.x * 32, k0 = blockIdx.y * 32;
    int tx = threadIdx.x, ty = threadIdx.y;       // 32 x 8
#pragma unroll
    for (int i = 0; i < 4; i++)
        tile[ty + i * 8][tx] = in[(size_t)(k0 + ty + i * 8) * N + n0 + tx];
    __syncthreads();
#pragma unroll
    for (int i = 0; i < 4; i++)
        out[(size_t)(n0 + ty + i * 8) * K + k0 + tx] = f2b(tile[tx][ty + i * 8]);
}

// ---------------------------------------------------------------------------
// 3a) Out-projection GEMM (kept: m97-style 128^2 tile, balanced at 512 blocks
// for N=1024). C fp32 = A @ BT + bias.
template <int MODE>
__global__ __launch_bounds__(256) void gemm_bt(
    const u16* __restrict__ A, const u16* __restrict__ BT,
    const float* __restrict__ bias,
    float* __restrict__ Cf, u16* __restrict__ Cqk, u16* __restrict__ Cvt,
    int M, int N, int K) {
    __shared__ u16 As[128 * 64];
    __shared__ u16 Bs[128 * 64];
    const int tid = threadIdx.x;
    const int w = tid >> 6, l = tid & 63;
    const int q = l >> 4, c = l & 15;
    const int m0 = blockIdx.y * 128, n0 = blockIdx.x * 128;
    const int wm = (w >> 1) * 64, wn = (w & 1) * 64;

    const int srow = w * 8 + (l >> 3);
    const int scol = ((l & 7) ^ (srow & 7)) * 8;   // u16 units
    const u16* gA = A + (size_t)(m0 + srow) * K + scol;
    const u16* gB = BT + (size_t)(n0 + srow) * K + scol;
    char* AsB = (char*)&As[0];
    char* BsB = (char*)&Bs[0];
    const int ldsOff = (w * 8) * 128;

    float4v acc[4][4];
#pragma unroll
    for (int i = 0; i < 4; i++)
#pragma unroll
        for (int j = 0; j < 4; j++) acc[i][j] = {0.f, 0.f, 0.f, 0.f};

    const int cs = c & 7;

    for (int k0 = 0; k0 < K; k0 += 64) {
        __syncthreads();
#pragma unroll
        for (int j = 0; j < 4; j++) {
            GLD16(gA + (size_t)(j * 32) * K + k0, AsB + ldsOff + j * 32 * 128);
            GLD16(gB + (size_t)(j * 32) * K + k0, BsB + ldsOff + j * 32 * 128);
        }
        __syncthreads();
#pragma unroll
        for (int kk = 0; kk < 2; kk++) {
            const int phys = ((kk * 4 + q) ^ cs) * 8;
            short8 af[4], bf[4];
#pragma unroll
            for (int mt = 0; mt < 4; mt++)
                af[mt] = *reinterpret_cast<const short8*>(&As[(wm + mt * 16 + c) * 64 + phys]);
#pragma unroll
            for (int nt = 0; nt < 4; nt++)
                bf[nt] = *reinterpret_cast<const short8*>(&Bs[(wn + nt * 16 + c) * 64 + phys]);
#pragma unroll
            for (int mt = 0; mt < 4; mt++)
#pragma unroll
                for (int nt = 0; nt < 4; nt++)
                    acc[mt][nt] = __builtin_amdgcn_mfma_f32_16x16x32_bf16(af[mt], bf[nt], acc[mt][nt], 0, 0, 0);
        }
    }

    const int q4 = q * 4;
    if (MODE == 0) {
#pragma unroll
        for (int nt = 0; nt < 4; nt++) {
            int col = n0 + wn + nt * 16 + c;
            float bv = bias[col];
#pragma unroll
            for (int mt = 0; mt < 4; mt++) {
                int row = m0 + wm + mt * 16 + q4;
#pragma unroll
                for (int r = 0; r < 4; r++)
                    Cf[(size_t)(row + r) * N + col] = acc[mt][nt][r] + bv;
            }
        }
    } else {
        bool isV = (n0 + wn) >= 2048;
        float qscale = ((n0 + wn) < 1024) ? (0.125f * 1.44269504f) : 1.0f;
#pragma unroll
        for (int nt = 0; nt < 4; nt++) {
            int col = n0 + wn + nt * 16 + c;
            float bv = bias[col];
            if (!isV) {
#pragma unroll
                for (int mt = 0; mt < 4; mt++) {
                    int row = m0 + wm + mt * 16 + q4;
#pragma unroll
                    for (int r = 0; r < 4; r++)
                        Cqk[(size_t)(row + r) * 2048 + col] = f2b((acc[mt][nt][r] + bv) * qscale);
                }
            } else {
                int hd_ = col - 2048;
#pragma unroll
                for (int mt = 0; mt < 4; mt++) {
                    int row = m0 + wm + mt * 16 + q4;
                    int bn = row >> 10, key = row & 1023;
                    ushort4 pk;
                    pk.x = f2b(acc[mt][nt][0] + bv);
                    pk.y = f2b(acc[mt][nt][1] + bv);
                    pk.z = f2b(acc[mt][nt][2] + bv);
                    pk.w = f2b(acc[mt][nt][3] + bv);
                    *reinterpret_cast<ushort4*>(
                        &Cvt[((size_t)(bn << 10) + hd_) * 1024 + key]) = pk;
                }
            }
        }
    }
}

// ---------------------------------------------------------------------------
// 3b) QKV GEMM: 256x256 tile, BK=64, 8 waves, 8-phase schedule with counted
// vmcnt (never 0 in steady state), st_16x32 LDS swizzle (pre-swizzled global
// source + swizzled ds_read chunk), setprio around MFMA clusters.
// Issue schedule is shifted so every LDS write is barrier-ordered >=1 phase
// after that slot's last ds_read (race-free by construction); waits are
// vmcnt(4) = 2 half-tiles in flight.
// Epilogue = MODE1 semantics: Q pre-scaled, Q/K -> Cqk bf16, V -> Cvt^T bf16.

#define READ_A(BUF, MH) do {                                                     \
    _Pragma("unroll") for (int mt = 0; mt < 4; mt++) {                           \
        _Pragma("unroll") for (int ks = 0; ks < 2; ks++)                         \
            af[mt][ks] = *reinterpret_cast<const short8*>(                       \
                &As[BUF][(wm + (MH) * 64 + mt * 16 + c) * 64 + kc0 + ks * 32]);  \
    }                                                                            \
} while (0)

#define READ_B(BUF, NH) do {                                                     \
    _Pragma("unroll") for (int nt = 0; nt < 2; nt++) {                           \
        _Pragma("unroll") for (int ks = 0; ks < 2; ks++)                         \
            bf[NH][nt][ks] = *reinterpret_cast<const short8*>(                   \
                &Bs[BUF][(wn + (NH) * 32 + nt * 16 + c) * 64 + kc0 + ks * 32]);  \
    }                                                                            \
} while (0)

#define MFMA_Q(MH, NH) do {                                                      \
    _Pragma("unroll") for (int mt = 0; mt < 4; mt++) {                           \
        _Pragma("unroll") for (int nt = 0; nt < 2; nt++) {                       \
            _Pragma("unroll") for (int ks = 0; ks < 2; ks++)                     \
                acc[(MH) * 4 + mt][(NH) * 2 + nt] =                              \
                    __builtin_amdgcn_mfma_f32_16x16x32_bf16(                     \
                        af[mt][ks], bf[NH][nt][ks],                              \
                        acc[(MH) * 4 + mt][(NH) * 2 + nt], 0, 0, 0);             \
        }                                                                        \
    }                                                                            \
} while (0)

#define PH_SYNC_MFMA(MH, NH) do {                                                \
    __builtin_amdgcn_s_barrier();                                                \
    asm volatile("s_waitcnt lgkmcnt(0)" ::: "memory");                           \
    __builtin_amdgcn_sched_barrier(0);                                           \
    __builtin_amdgcn_s_setprio(1);                                               \
    MFMA_Q(MH, NH);                                                              \
    __builtin_amdgcn_sched_barrier(0);                                           \
    __builtin_amdgcn_s_setprio(0);                                               \
    __builtin_amdgcn_s_barrier();                                                \
} while (0)

__global__ __launch_bounds__(512, 2) void gemm_qkv256(
    const u16* __restrict__ A, const u16* __restrict__ BT,
    const float* __restrict__ bias,
    u16* __restrict__ Cqk, u16* __restrict__ Cvt,
    int M, int N, int K) {
    __shared__ u16 As[2][16384];   // 2 buf x 256 rows x 64 cols
    __shared__ u16 Bs[2][16384];
    const int tid = threadIdx.x;
    const int w = tid >> 6, l = tid & 63;
    const int q = l >> 4, c = l & 15;
    const int m0 = blockIdx.y * 256, n0 = blockIdx.x * 256;
    const int wm = (w >> 2) * 128, wn = (w & 3) * 64;

    // staging: thread covers row rA (of a 64-row issue block), 16B chunk tid&7.
    // st_16x32 source pre-swizzle: src chunk = ch ^ ((row>>2&1)<<1).
    const int rA = tid >> 3;                                   // 0..63
    const int chS = ((tid & 7) ^ (((tid >> 5) & 1) << 1)) << 3; // u16
    const u16* gA = A + (size_t)(m0 + rA) * K + chS;
    const u16* gB = BT + (size_t)(n0 + rA) * K + chS;
    const int lbase = (w * 8) * 64;                            // u16, wave-uniform

    auto issueA = [&](int buf, int kt, int h) {
        const u16* g = gA + (size_t)(h * 128) * K + kt * 64;
        u16* lp = &As[buf][h * 8192 + lbase];
        GLD16(g, lp);
        GLD16(g + (size_t)64 * K, lp + 4096);
    };
    auto issueB = [&](int buf, int kt, int h) {
        const u16* g = gB + (size_t)(h * 128) * K + kt * 64;
        u16* lp = &Bs[buf][h * 8192 + lbase];
        GLD16(g, lp);
        GLD16(g + (size_t)64 * K, lp + 4096);
    };

    // frag-read de-swizzle: chunk = (ks*4+q) ^ sw2, sw2 from row bit2 (== c bit2)
    const int sw2 = ((c >> 2) & 1) << 1;
    const int kc0 = (q ^ sw2) << 3;                            // u16

    float4v acc[8][4];
#pragma unroll
    for (int i = 0; i < 8; i++)
#pragma unroll
        for (int j = 0; j < 4; j++) acc[i][j] = {0.f, 0.f, 0.f, 0.f};

    short8 af[4][2];       // A half (mh) x 4 m-frags x 2 k-halves
    short8 bf[2][2][2];    // both B halves x 2 n-frags x 2 k-halves

    // prologue: tile0 {B-lo,B-hi,A-lo,A-hi}, tile1 {B-lo,B-hi}; wait tile0.
    issueB(0, 0, 0); issueB(0, 0, 1); issueA(0, 0, 0); issueA(0, 0, 1);
    issueB(1, 1, 0); issueB(1, 1, 1);
    asm volatile("s_waitcnt vmcnt(4)" ::: "memory");
    __builtin_amdgcn_s_barrier();

    for (int it = 0; it < 7; ++it) {            // tiles 0..13
        const int t1 = 2 * it + 1, t2 = 2 * it + 2, t3 = 2 * it + 3;
        // ---- tile 2it (buf0) ----
        READ_A(0, 0); READ_B(0, 0);
        issueA(1, t1, 0);                       // buf1 A-lo (buf1 A read ended prev P7)
        PH_SYNC_MFMA(0, 0);

        READ_B(0, 1);
        issueA(1, t1, 1);                       // buf1 A-hi
        PH_SYNC_MFMA(0, 1);

        READ_A(0, 1);
        issueB(0, t2, 0);                       // buf0 B-lo (buf0 B read ended P2)
        PH_SYNC_MFMA(1, 1);

        issueB(0, t2, 1);                       // buf0 B-hi
        asm volatile("s_waitcnt vmcnt(4)" ::: "memory");  // tile t1 fully landed
        PH_SYNC_MFMA(1, 0);

        // ---- tile 2it+1 (buf1) ----
        READ_A(1, 0); READ_B(1, 0);
        issueA(0, t2, 0);                       // buf0 A-lo (buf0 A read ended P3)
        PH_SYNC_MFMA(0, 0);

        READ_B(1, 1);
        issueA(0, t2, 1);                       // buf0 A-hi
        PH_SYNC_MFMA(0, 1);

        READ_A(1, 1);
        issueB(1, t3, 0);                       // buf1 B-lo (buf1 B read ended P6)
        PH_SYNC_MFMA(1, 1);

        issueB(1, t3, 1);                       // buf1 B-hi
        asm volatile("s_waitcnt vmcnt(4)" ::: "memory");  // tile t2 fully landed
        PH_SYNC_MFMA(1, 0);
    }

    // ---- epilogue: tiles 14 (buf0), 15 (buf1) ----
    READ_A(0, 0); READ_B(0, 0);
    issueA(1, 15, 0);
    PH_SYNC_MFMA(0, 0);

    READ_B(0, 1);
    issueA(1, 15, 1);
    PH_SYNC_MFMA(0, 1);

    READ_A(0, 1);
    PH_SYNC_MFMA(1, 1);

    asm volatile("s_waitcnt vmcnt(0)" ::: "memory");    // tile 15 fully landed
    PH_SYNC_MFMA(1, 0);

    READ_A(1, 0); READ_B(1, 0);
    PH_SYNC_MFMA(0, 0);

    READ_B(1, 1);
    PH_SYNC_MFMA(0, 1);

    READ_A(1, 1);
    PH_SYNC_MFMA(1, 1);

    MFMA_Q(1, 0);   // regs already waited in P7

    // ---- C write: QKV split epilogue ----
    const bool isV = (n0 + wn) >= 2048;                    // wave-uniform
    const float qscale = ((n0 + wn) < 1024) ? (0.125f * 1.44269504f) : 1.0f;
    const int q4 = q * 4;
#pragma unroll
    for (int ni = 0; ni < 4; ni++) {
        int col = n0 + wn + ni * 16 + c;
        float bv = bias[col];
        if (!isV) {
#pragma unroll
            for (int mi = 0; mi < 8; mi++) {
                int row = m0 + wm + mi * 16 + q4;
#pragma unroll
                for (int r = 0; r < 4; r++)
                    Cqk[(size_t)(row + r) * 2048 + col] = f2b((acc[mi][ni][r] + bv) * qscale);
            }
        } else {
            int hd_ = col - 2048;                          // h*64 + d
#pragma unroll
            for (int mi = 0; mi < 8; mi++) {
                int row = m0 + wm + mi * 16 + q4;          // multiple of 4
                int bn = row >> 10, key = row & 1023;
                ushort4 pk;
                pk.x = f2b(acc[mi][ni][0] + bv);
                pk.y = f2b(acc[mi][ni][1] + bv);
                pk.z = f2b(acc[mi][ni][2] + bv);
                pk.w = f2b(acc[mi][ni][3] + bv);
                *reinterpret_cast<ushort4*>(
                    &Cvt[((size_t)(bn << 10) + hd_) * 1024 + key]) = pk;
            }
        }
    }
}

// ---------------------------------------------------------------------------
// 4) Flash attention per (bn, h), max-free softmax, LDS K/V with register
//    prefetch; ones-column row-sums via MFMA. Grid: x=combo (128), y=qtile (8)
//    so all q-tiles of a combo land on one XCD (idx%8 == combo%8) -> L2 reuse.
__global__ __launch_bounds__(256) void attn(const u16* __restrict__ qk,
                                            const u16* __restrict__ vt,
                                            u16* __restrict__ ob) {
    __shared__ u16 Ks[64 * 72];
    __shared__ u16 Vs[64 * 72];
    __shared__ u16 Ps[128 * 72];
    const int tid = threadIdx.x;
    const int w = tid >> 6, l = tid & 63, q = l >> 4, c = l & 15;
    const int combo = blockIdx.x, qtile = blockIdx.y;
    const int bn = combo >> 4, h = combo & 15;
    const int t0 = bn << 10;
    const int qoff = h << 6;
    const int koff = 1024 + (h << 6);
    const int vrow0 = combo << 6;
    const int qrow_base = t0 + qtile * 128 + w * 32;

    short8 v1;
    {
        u16 one = (c == 0) ? (u16)0x3F80 : (u16)0;
#pragma unroll
        for (int j = 0; j < 8; j++) v1[j] = (short)one;
    }

    short8 aq[2][2];
#pragma unroll
    for (int mt = 0; mt < 2; mt++)
#pragma unroll
        for (int ks = 0; ks < 2; ks++)
            aq[mt][ks] = *reinterpret_cast<const short8*>(
                qk + (size_t)(qrow_base + mt * 16 + c) * 2048 + qoff + ks * 32 + q * 8);

    float4v o_acc[2][4];
    float4v osum[2];
#pragma unroll
    for (int mt = 0; mt < 2; mt++) {
#pragma unroll
        for (int nt = 0; nt < 4; nt++) o_acc[mt][nt] = {0.f, 0.f, 0.f, 0.f};
        osum[mt] = {0.f, 0.f, 0.f, 0.f};
    }

    const int sr = tid >> 3;
    const int sc = (tid & 7) * 8;

    uint4v kreg[2], vreg[2];
#pragma unroll
    for (int i = 0; i < 2; i++) {
        int r = sr + i * 32;
        kreg[i] = *reinterpret_cast<const uint4v*>(
            qk + (size_t)(t0 + r) * 2048 + koff + sc);
        vreg[i] = *reinterpret_cast<const uint4v*>(
            vt + (size_t)(vrow0 + r) * 1024 + sc);
    }
#pragma unroll
    for (int i = 0; i < 2; i++) {
        int r = sr + i * 32;
        *reinterpret_cast<uint4v*>(&Ks[r * 72 + sc]) = kreg[i];
        *reinterpret_cast<uint4v*>(&Vs[r * 72 + sc]) = vreg[i];
    }
    __syncthreads();

    for (int chunk = 0; chunk < 16; chunk++) {
        if (chunk < 15) {
            const int key0n = (chunk + 1) * 64;
#pragma unroll
            for (int i = 0; i < 2; i++) {
                int r = sr + i * 32;
                kreg[i] = *reinterpret_cast<const uint4v*>(
                    qk + (size_t)(t0 + key0n + r) * 2048 + koff + sc);
                vreg[i] = *reinterpret_cast<const uint4v*>(
                    vt + (size_t)(vrow0 + r) * 1024 + key0n + sc);
            }
        }

        float4v s[2][4];
#pragma unroll
        for (int mt = 0; mt < 2; mt++)
#pragma unroll
            for (int nt = 0; nt < 4; nt++) s[mt][nt] = {0.f, 0.f, 0.f, 0.f};
#pragma unroll
        for (int ks = 0; ks < 2; ks++) {
            short8 bk[4];
#pragma unroll
            for (int nt = 0; nt < 4; nt++)
                bk[nt] = *reinterpret_cast<const short8*>(&Ks[(nt * 16 + c) * 72 + ks * 32 + q * 8]);
#pragma unroll
            for (int mt = 0; mt < 2; mt++)
#pragma unroll
                for (int nt = 0; nt < 4; nt++)
                    s[mt][nt] = __builtin_amdgcn_mfma_f32_16x16x32_bf16(aq[mt][ks], bk[nt], s[mt][nt], 0, 0, 0);
        }

#pragma unroll
        for (int mt = 0; mt < 2; mt++)
#pragma unroll
            for (int r = 0; r < 4; r++)
#pragma unroll
                for (int nt = 0; nt < 4; nt++)
                    Ps[(w * 32 + mt * 16 + q * 4 + r) * 72 + nt * 16 + c] =
                        f2b(EXP2F(s[mt][nt][r]));

#pragma unroll
        for (int ks = 0; ks < 2; ks++) {
            short8 pf[2], vf[4];
#pragma unroll
            for (int mt = 0; mt < 2; mt++)
                pf[mt] = *reinterpret_cast<const short8*>(
                    &Ps[(w * 32 + mt * 16 + c) * 72 + ks * 32 + q * 8]);
#pragma unroll
            for (int nt = 0; nt < 4; nt++)
                vf[nt] = *reinterpret_cast<const short8*>(&Vs[(nt * 16 + c) * 72 + ks * 32 + q * 8]);
#pragma unroll
            for (int mt = 0; mt < 2; mt++) {
#pragma unroll
                for (int nt = 0; nt < 4; nt++)
                    o_acc[mt][nt] = __builtin_amdgcn_mfma_f32_16x16x32_bf16(pf[mt], vf[nt], o_acc[mt][nt], 0, 0, 0);
                osum[mt] = __builtin_amdgcn_mfma_f32_16x16x32_bf16(pf[mt], v1, osum[mt], 0, 0, 0);
            }
        }

        if (chunk < 15) {
            __syncthreads();
#pragma unroll
            for (int i = 0; i < 2; i++) {
                int r = sr + i * 32;
                *reinterpret_cast<uint4v*>(&Ks[r * 72 + sc]) = kreg[i];
                *reinterpret_cast<uint4v*>(&Vs[r * 72 + sc]) = vreg[i];
            }
            __syncthreads();
        }
    }

#pragma unroll
    for (int mt = 0; mt < 2; mt++) {
        float inv[4];
#pragma unroll
        for (int r = 0; r < 4; r++) {
            float lv = __shfl(osum[mt][r], tid & 48);
            inv[r] = 1.0f / lv;
        }
#pragma unroll
        for (int nt = 0; nt < 4; nt++)
#pragma unroll
            for (int r = 0; r < 4; r++) {
                int row = qrow_base + mt * 16 + q * 4 + r;
                int col = (h << 6) + nt * 16 + c;
                ob[(size_t)row * 1024 + col] = f2b(o_acc[mt][nt][r] * inv[r]);
            }
    }
}

// ---------------------------------------------------------------------------
extern "C" void kernel_launch(void* const* d_in, const int* in_sizes, int n_in,
                              void* d_out, int out_size, void* d_ws, size_t ws_size,
                              hipStream_t stream) {
    const float* x    = (const float*)d_in[0];
    const float* wqkv = (const float*)d_in[1];
    const float* bqkv = (const float*)d_in[2];
    const float* wo   = (const float*)d_in[3];
    const float* bo   = (const float*)d_in[4];
    float* out = (float*)d_out;
    char* ws = (char*)d_ws;

    u16* xb    = (u16*)(ws);                 // [8192][1024]  16.8 MB
    u16* wqkvT = (u16*)(ws + 16777216);      // [3072][1024]   6.3 MB
    u16* woT   = (u16*)(ws + 23068672);      // [1024][1024]   2.1 MB
    u16* qkb   = (u16*)(ws + 25165824);      // [8192][2048]  33.6 MB
    u16* vtb   = (u16*)(ws + 58720256);      // [8192][1024]  16.8 MB (V^T per combo)
    u16* obuf  = (u16*)(ws + 75497472);      // [8192][1024]  16.8 MB
    // total 92.3 MB

    convert_x<<<8192, 256, 0, stream>>>(x, xb);
    transpose_convert<<<dim3(96, 32), dim3(32, 8), 0, stream>>>(wqkv, wqkvT, 1024, 3072);
    transpose_convert<<<dim3(32, 32), dim3(32, 8), 0, stream>>>(wo, woT, 1024, 1024);
    gemm_qkv256<<<dim3(12, 32), 512, 0, stream>>>(xb, wqkvT, bqkv,
                                                  qkb, vtb, 8192, 3072, 1024);
    attn<<<dim3(128, 8), 256, 0, stream>>>(qkb, vtb, obuf);
    gemm_bt<0><<<dim3(8, 64), 256, 0, stream>>>(obuf, woT, bo,
                                                out, nullptr, nullptr, 8192, 1024, 1024);
}

// Round 2
// 267.636 us; speedup vs baseline: 1.0510x; 1.0510x over previous
//
#include <hip/hip_runtime.h>
#include <hip/hip_bf16.h>
#include <stdint.h>

typedef __attribute__((ext_vector_type(8))) short short8;
typedef __attribute__((ext_vector_type(4))) float float4v;
typedef __attribute__((ext_vector_type(4))) unsigned int uint4v;
typedef unsigned short u16;

#if __has_builtin(__builtin_amdgcn_exp2f)
#define EXP2F(x) __builtin_amdgcn_exp2f(x)
#else
#define EXP2F(x) __expf(0.69314718056f * (x))
#endif

__device__ __forceinline__ u16 f2b(float f) {
    union { __hip_bfloat16 b; u16 u; } cv;
    cv.b = __float2bfloat16(f);
    return cv.u;
}

#define GLD16(g, l) __builtin_amdgcn_global_load_lds( \
    (const __attribute__((address_space(1))) void*)(g), \
    (__attribute__((address_space(3))) void*)(l), 16, 0, 0)

// ---------------------------------------------------------------------------
// 1) Gather even rows of x (token t <- x row 2t) and convert fp32 -> bf16.
__global__ void convert_x(const float* __restrict__ x, u16* __restrict__ xb) {
    int id = blockIdx.x * 256 + threadIdx.x;
    int row = id >> 8;
    int c4 = id & 255;
    const float4* src = reinterpret_cast<const float4*>(x + (size_t)(2 * row) * 1024) + c4;
    float4 v = *src;
    ushort4 o;
    o.x = f2b(v.x); o.y = f2b(v.y); o.z = f2b(v.z); o.w = f2b(v.w);
    *(reinterpret_cast<ushort4*>(xb + (size_t)row * 1024) + c4) = o;
}

// ---------------------------------------------------------------------------
// 2) Transpose-convert: in fp32 [K][N] -> out bf16 [N][K].
__global__ void transpose_convert(const float* __restrict__ in, u16* __restrict__ out,
                                  int K, int N) {
    __shared__ float tile[32][33];
    int n0 = blockIdx.x * 32, k0 = blockIdx.y * 32;
    int tx = threadIdx.x, ty = threadIdx.y;       // 32 x 8
#pragma unroll
    for (int i = 0; i < 4; i++)
        tile[ty + i * 8][tx] = in[(size_t)(k0 + ty + i * 8) * N + n0 + tx];
    __syncthreads();
#pragma unroll
    for (int i = 0; i < 4; i++)
        out[(size_t)(n0 + ty + i * 8) * K + k0 + tx] = f2b(tile[tx][ty + i * 8]);
}

// ---------------------------------------------------------------------------
// 3a) Out-projection GEMM (m97-style 128^2 tile, balanced at 512 blocks
// for N=1024). C fp32 = A @ BT + bias.
template <int MODE>
__global__ __launch_bounds__(256) void gemm_bt(
    const u16* __restrict__ A, const u16* __restrict__ BT,
    const float* __restrict__ bias,
    float* __restrict__ Cf, u16* __restrict__ Cqk, u16* __restrict__ Cvt,
    int M, int N, int K) {
    __shared__ u16 As[128 * 64];
    __shared__ u16 Bs[128 * 64];
    const int tid = threadIdx.x;
    const int w = tid >> 6, l = tid & 63;
    const int q = l >> 4, c = l & 15;
    const int m0 = blockIdx.y * 128, n0 = blockIdx.x * 128;
    const int wm = (w >> 1) * 64, wn = (w & 1) * 64;

    const int srow = w * 8 + (l >> 3);
    const int scol = ((l & 7) ^ (srow & 7)) * 8;   // u16 units
    const u16* gA = A + (size_t)(m0 + srow) * K + scol;
    const u16* gB = BT + (size_t)(n0 + srow) * K + scol;
    char* AsB = (char*)&As[0];
    char* BsB = (char*)&Bs[0];
    const int ldsOff = (w * 8) * 128;

    float4v acc[4][4];
#pragma unroll
    for (int i = 0; i < 4; i++)
#pragma unroll
        for (int j = 0; j < 4; j++) acc[i][j] = {0.f, 0.f, 0.f, 0.f};

    const int cs = c & 7;

    for (int k0 = 0; k0 < K; k0 += 64) {
        __syncthreads();
#pragma unroll
        for (int j = 0; j < 4; j++) {
            GLD16(gA + (size_t)(j * 32) * K + k0, AsB + ldsOff + j * 32 * 128);
            GLD16(gB + (size_t)(j * 32) * K + k0, BsB + ldsOff + j * 32 * 128);
        }
        __syncthreads();
#pragma unroll
        for (int kk = 0; kk < 2; kk++) {
            const int phys = ((kk * 4 + q) ^ cs) * 8;
            short8 af[4], bf[4];
#pragma unroll
            for (int mt = 0; mt < 4; mt++)
                af[mt] = *reinterpret_cast<const short8*>(&As[(wm + mt * 16 + c) * 64 + phys]);
#pragma unroll
            for (int nt = 0; nt < 4; nt++)
                bf[nt] = *reinterpret_cast<const short8*>(&Bs[(wn + nt * 16 + c) * 64 + phys]);
#pragma unroll
            for (int mt = 0; mt < 4; mt++)
#pragma unroll
                for (int nt = 0; nt < 4; nt++)
                    acc[mt][nt] = __builtin_amdgcn_mfma_f32_16x16x32_bf16(af[mt], bf[nt], acc[mt][nt], 0, 0, 0);
        }
    }

    const int q4 = q * 4;
    if (MODE == 0) {
#pragma unroll
        for (int nt = 0; nt < 4; nt++) {
            int col = n0 + wn + nt * 16 + c;
            float bv = bias[col];
#pragma unroll
            for (int mt = 0; mt < 4; mt++) {
                int row = m0 + wm + mt * 16 + q4;
#pragma unroll
                for (int r = 0; r < 4; r++)
                    Cf[(size_t)(row + r) * N + col] = acc[mt][nt][r] + bv;
            }
        }
    } else {
        bool isV = (n0 + wn) >= 2048;
        float qscale = ((n0 + wn) < 1024) ? (0.125f * 1.44269504f) : 1.0f;
#pragma unroll
        for (int nt = 0; nt < 4; nt++) {
            int col = n0 + wn + nt * 16 + c;
            float bv = bias[col];
            if (!isV) {
#pragma unroll
                for (int mt = 0; mt < 4; mt++) {
                    int row = m0 + wm + mt * 16 + q4;
#pragma unroll
                    for (int r = 0; r < 4; r++)
                        Cqk[(size_t)(row + r) * 2048 + col] = f2b((acc[mt][nt][r] + bv) * qscale);
                }
            } else {
                int hd_ = col - 2048;
#pragma unroll
                for (int mt = 0; mt < 4; mt++) {
                    int row = m0 + wm + mt * 16 + q4;
                    int bn = row >> 10, key = row & 1023;
                    ushort4 pk;
                    pk.x = f2b(acc[mt][nt][0] + bv);
                    pk.y = f2b(acc[mt][nt][1] + bv);
                    pk.z = f2b(acc[mt][nt][2] + bv);
                    pk.w = f2b(acc[mt][nt][3] + bv);
                    *reinterpret_cast<ushort4*>(
                        &Cvt[((size_t)(bn << 10) + hd_) * 1024 + key]) = pk;
                }
            }
        }
    }
}

// ---------------------------------------------------------------------------
// 3b) QKV GEMM: 256x256 tile, BK=64, 8 waves, 8-phase schedule with counted
// vmcnt (never 0 in steady state), setprio around MFMA clusters.
// LDS swizzle: FULL 3-bit XOR (chunk ^= row&7) -- r1 post-mortem: 1-bit XOR
// left an 8-way bank conflict (4.7M cycles); 3-bit spreads a fragment-read's
// 16 lanes over all 8 chunks (2 lanes/chunk = free, m136). Applied as
// pre-swizzled GLOBAL source (global_load_lds dest must stay lane-linear) +
// matching XOR on the ds_read chunk (same involution both sides).
// Issue schedule keeps every LDS write barrier-ordered >=1 full phase after
// that slot's last ds_read (race-free by construction); vmcnt(4) at phases
// 4/8 = 2 half-tiles in flight.

#define READ_A(BUF, MH) do {                                                     \
    _Pragma("unroll") for (int mt = 0; mt < 4; mt++) {                           \
        _Pragma("unroll") for (int ks = 0; ks < 2; ks++)                         \
            af[mt][ks] = *reinterpret_cast<const short8*>(                       \
                &As[BUF][(wm + (MH) * 64 + mt * 16 + c) * 64 + kofs[ks]]);       \
    }                                                                            \
} while (0)

#define READ_B(BUF, NH) do {                                                     \
    _Pragma("unroll") for (int nt = 0; nt < 2; nt++) {                           \
        _Pragma("unroll") for (int ks = 0; ks < 2; ks++)                         \
            bf[NH][nt][ks] = *reinterpret_cast<const short8*>(                   \
                &Bs[BUF][(wn + (NH) * 32 + nt * 16 + c) * 64 + kofs[ks]]);       \
    }                                                                            \
} while (0)

#define MFMA_Q(MH, NH) do {                                                      \
    _Pragma("unroll") for (int mt = 0; mt < 4; mt++) {                           \
        _Pragma("unroll") for (int nt = 0; nt < 2; nt++) {                       \
            _Pragma("unroll") for (int ks = 0; ks < 2; ks++)                     \
                acc[(MH) * 4 + mt][(NH) * 2 + nt] =                              \
                    __builtin_amdgcn_mfma_f32_16x16x32_bf16(                     \
                        af[mt][ks], bf[NH][nt][ks],                              \
                        acc[(MH) * 4 + mt][(NH) * 2 + nt], 0, 0, 0);             \
        }                                                                        \
    }                                                                            \
} while (0)

#define PH_SYNC_MFMA(MH, NH) do {                                                \
    __builtin_amdgcn_s_barrier();                                                \
    asm volatile("s_waitcnt lgkmcnt(0)" ::: "memory");                           \
    __builtin_amdgcn_sched_barrier(0);                                           \
    __builtin_amdgcn_s_setprio(1);                                               \
    MFMA_Q(MH, NH);                                                              \
    __builtin_amdgcn_sched_barrier(0);                                           \
    __builtin_amdgcn_s_setprio(0);                                               \
    __builtin_amdgcn_s_barrier();                                                \
} while (0)

__global__ __launch_bounds__(512, 2) void gemm_qkv256(
    const u16* __restrict__ A, const u16* __restrict__ BT,
    const float* __restrict__ bias,
    u16* __restrict__ Cqk, u16* __restrict__ Cvt,
    int M, int N, int K) {
    __shared__ u16 As[2][16384];   // 2 buf x 256 rows x 64 cols
    __shared__ u16 Bs[2][16384];
    const int tid = threadIdx.x;
    const int w = tid >> 6, l = tid & 63;
    const int q = l >> 4, c = l & 15;
    const int m0 = blockIdx.y * 256, n0 = blockIdx.x * 256;
    const int wm = (w >> 2) * 128, wn = (w & 3) * 64;

    // staging: thread covers LDS row rA (of a 64-row issue block), phys 16B
    // chunk tid&7. Source global chunk = (tid&7) ^ (rA&7)  [3-bit XOR].
    const int rA = tid >> 3;                                       // 0..63
    const int chS = ((tid & 7) ^ (rA & 7)) << 3;                   // u16 units
    const u16* gA = A + (size_t)(m0 + rA) * K + chS;
    const u16* gB = BT + (size_t)(n0 + rA) * K + chS;
    const int lbase = (w * 8) * 64;                                // u16, wave-uniform

    auto issueA = [&](int buf, int kt, int h) {
        const u16* g = gA + (size_t)(h * 128) * K + kt * 64;
        u16* lp = &As[buf][h * 8192 + lbase];
        GLD16(g, lp);
        GLD16(g + (size_t)64 * K, lp + 4096);
    };
    auto issueB = [&](int buf, int kt, int h) {
        const u16* g = gB + (size_t)(h * 128) * K + kt * 64;
        u16* lp = &Bs[buf][h * 8192 + lbase];
        GLD16(g, lp);
        GLD16(g + (size_t)64 * K, lp + 4096);
    };

    // frag-read de-swizzle: phys chunk = (ks*4 + q) ^ (c&7); row&7 == c&7
    // because fragment rows are (16-aligned + c).
    const int kofs[2] = { ((q ^ (c & 7)) << 3), (((q + 4) ^ (c & 7)) << 3) };

    float4v acc[8][4];
#pragma unroll
    for (int i = 0; i < 8; i++)
#pragma unroll
        for (int j = 0; j < 4; j++) acc[i][j] = {0.f, 0.f, 0.f, 0.f};

    short8 af[4][2];       // A half (mh) x 4 m-frags x 2 k-halves
    short8 bf[2][2][2];    // both B halves x 2 n-frags x 2 k-halves

    // prologue: tile0 {B-lo,B-hi,A-lo,A-hi}, tile1 {B-lo,B-hi}; wait tile0.
    issueB(0, 0, 0); issueB(0, 0, 1); issueA(0, 0, 0); issueA(0, 0, 1);
    issueB(1, 1, 0); issueB(1, 1, 1);
    asm volatile("s_waitcnt vmcnt(4)" ::: "memory");
    __builtin_amdgcn_s_barrier();

    for (int it = 0; it < 7; ++it) {            // tiles 0..13
        const int t1 = 2 * it + 1, t2 = 2 * it + 2, t3 = 2 * it + 3;
        // ---- tile 2it (buf0) ----
        READ_A(0, 0); READ_B(0, 0);
        issueA(1, t1, 0);                       // buf1 A-lo (buf1 A read ended prev P7)
        PH_SYNC_MFMA(0, 0);

        READ_B(0, 1);
        issueA(1, t1, 1);                       // buf1 A-hi
        PH_SYNC_MFMA(0, 1);

        READ_A(0, 1);
        issueB(0, t2, 0);                       // buf0 B-lo (buf0 B read ended P2)
        PH_SYNC_MFMA(1, 1);

        issueB(0, t2, 1);                       // buf0 B-hi
        asm volatile("s_waitcnt vmcnt(4)" ::: "memory");  // tile t1 fully landed
        PH_SYNC_MFMA(1, 0);

        // ---- tile 2it+1 (buf1) ----
        READ_A(1, 0); READ_B(1, 0);
        issueA(0, t2, 0);                       // buf0 A-lo (buf0 A read ended P3)
        PH_SYNC_MFMA(0, 0);

        READ_B(1, 1);
        issueA(0, t2, 1);                       // buf0 A-hi
        PH_SYNC_MFMA(0, 1);

        READ_A(1, 1);
        issueB(1, t3, 0);                       // buf1 B-lo (buf1 B read ended P6)
        PH_SYNC_MFMA(1, 1);

        issueB(1, t3, 1);                       // buf1 B-hi
        asm volatile("s_waitcnt vmcnt(4)" ::: "memory");  // tile t2 fully landed
        PH_SYNC_MFMA(1, 0);
    }

    // ---- epilogue: tiles 14 (buf0), 15 (buf1) ----
    READ_A(0, 0); READ_B(0, 0);
    issueA(1, 15, 0);
    PH_SYNC_MFMA(0, 0);

    READ_B(0, 1);
    issueA(1, 15, 1);
    PH_SYNC_MFMA(0, 1);

    READ_A(0, 1);
    PH_SYNC_MFMA(1, 1);

    asm volatile("s_waitcnt vmcnt(0)" ::: "memory");    // tile 15 fully landed
    PH_SYNC_MFMA(1, 0);

    READ_A(1, 0); READ_B(1, 0);
    PH_SYNC_MFMA(0, 0);

    READ_B(1, 1);
    PH_SYNC_MFMA(0, 1);

    READ_A(1, 1);
    PH_SYNC_MFMA(1, 1);

    MFMA_Q(1, 0);   // regs already waited in P7

    // ---- C write: QKV split epilogue ----
    const bool isV = (n0 + wn) >= 2048;                    // wave-uniform
    const float qscale = ((n0 + wn) < 1024) ? (0.125f * 1.44269504f) : 1.0f;
    const int q4 = q * 4;
#pragma unroll
    for (int ni = 0; ni < 4; ni++) {
        int col = n0 + wn + ni * 16 + c;
        float bv = bias[col];
        if (!isV) {
#pragma unroll
            for (int mi = 0; mi < 8; mi++) {
                int row = m0 + wm + mi * 16 + q4;
#pragma unroll
                for (int r = 0; r < 4; r++)
                    Cqk[(size_t)(row + r) * 2048 + col] = f2b((acc[mi][ni][r] + bv) * qscale);
            }
        } else {
            int hd_ = col - 2048;                          // h*64 + d
#pragma unroll
            for (int mi = 0; mi < 8; mi++) {
                int row = m0 + wm + mi * 16 + q4;          // multiple of 4
                int bn = row >> 10, key = row & 1023;
                ushort4 pk;
                pk.x = f2b(acc[mi][ni][0] + bv);
                pk.y = f2b(acc[mi][ni][1] + bv);
                pk.z = f2b(acc[mi][ni][2] + bv);
                pk.w = f2b(acc[mi][ni][3] + bv);
                *reinterpret_cast<ushort4*>(
                    &Cvt[((size_t)(bn << 10) + hd_) * 1024 + key]) = pk;
            }
        }
    }
}

// ---------------------------------------------------------------------------
// 4) Flash attention per (bn, h), max-free softmax, LDS K/V with register
//    prefetch; ones-column row-sums via MFMA. Grid: x=combo (128), y=qtile (8)
//    so all q-tiles of a combo land on one XCD (idx%8 == combo%8) -> L2 reuse.
__global__ __launch_bounds__(256) void attn(const u16* __restrict__ qk,
                                            const u16* __restrict__ vt,
                                            u16* __restrict__ ob) {
    __shared__ u16 Ks[64 * 72];
    __shared__ u16 Vs[64 * 72];
    __shared__ u16 Ps[128 * 72];
    const int tid = threadIdx.x;
    const int w = tid >> 6, l = tid & 63, q = l >> 4, c = l & 15;
    const int combo = blockIdx.x, qtile = blockIdx.y;
    const int bn = combo >> 4, h = combo & 15;
    const int t0 = bn << 10;
    const int qoff = h << 6;
    const int koff = 1024 + (h << 6);
    const int vrow0 = combo << 6;
    const int qrow_base = t0 + qtile * 128 + w * 32;

    short8 v1;
    {
        u16 one = (c == 0) ? (u16)0x3F80 : (u16)0;
#pragma unroll
        for (int j = 0; j < 8; j++) v1[j] = (short)one;
    }

    short8 aq[2][2];
#pragma unroll
    for (int mt = 0; mt < 2; mt++)
#pragma unroll
        for (int ks = 0; ks < 2; ks++)
            aq[mt][ks] = *reinterpret_cast<const short8*>(
                qk + (size_t)(qrow_base + mt * 16 + c) * 2048 + qoff + ks * 32 + q * 8);

    float4v o_acc[2][4];
    float4v osum[2];
#pragma unroll
    for (int mt = 0; mt < 2; mt++) {
#pragma unroll
        for (int nt = 0; nt < 4; nt++) o_acc[mt][nt] = {0.f, 0.f, 0.f, 0.f};
        osum[mt] = {0.f, 0.f, 0.f, 0.f};
    }

    const int sr = tid >> 3;
    const int sc = (tid & 7) * 8;

    uint4v kreg[2], vreg[2];
#pragma unroll
    for (int i = 0; i < 2; i++) {
        int r = sr + i * 32;
        kreg[i] = *reinterpret_cast<const uint4v*>(
            qk + (size_t)(t0 + r) * 2048 + koff + sc);
        vreg[i] = *reinterpret_cast<const uint4v*>(
            vt + (size_t)(vrow0 + r) * 1024 + sc);
    }
#pragma unroll
    for (int i = 0; i < 2; i++) {
        int r = sr + i * 32;
        *reinterpret_cast<uint4v*>(&Ks[r * 72 + sc]) = kreg[i];
        *reinterpret_cast<uint4v*>(&Vs[r * 72 + sc]) = vreg[i];
    }
    __syncthreads();

    for (int chunk = 0; chunk < 16; chunk++) {
        if (chunk < 15) {
            const int key0n = (chunk + 1) * 64;
#pragma unroll
            for (int i = 0; i < 2; i++) {
                int r = sr + i * 32;
                kreg[i] = *reinterpret_cast<const uint4v*>(
                    qk + (size_t)(t0 + key0n + r) * 2048 + koff + sc);
                vreg[i] = *reinterpret_cast<const uint4v*>(
                    vt + (size_t)(vrow0 + r) * 1024 + key0n + sc);
            }
        }

        float4v s[2][4];
#pragma unroll
        for (int mt = 0; mt < 2; mt++)
#pragma unroll
            for (int nt = 0; nt < 4; nt++) s[mt][nt] = {0.f, 0.f, 0.f, 0.f};
#pragma unroll
        for (int ks = 0; ks < 2; ks++) {
            short8 bk[4];
#pragma unroll
            for (int nt = 0; nt < 4; nt++)
                bk[nt] = *reinterpret_cast<const short8*>(&Ks[(nt * 16 + c) * 72 + ks * 32 + q * 8]);
#pragma unroll
            for (int mt = 0; mt < 2; mt++)
#pragma unroll
                for (int nt = 0; nt < 4; nt++)
                    s[mt][nt] = __builtin_amdgcn_mfma_f32_16x16x32_bf16(aq[mt][ks], bk[nt], s[mt][nt], 0, 0, 0);
        }

#pragma unroll
        for (int mt = 0; mt < 2; mt++)
#pragma unroll
            for (int r = 0; r < 4; r++)
#pragma unroll
                for (int nt = 0; nt < 4; nt++)
                    Ps[(w * 32 + mt * 16 + q * 4 + r) * 72 + nt * 16 + c] =
                        f2b(EXP2F(s[mt][nt][r]));

#pragma unroll
        for (int ks = 0; ks < 2; ks++) {
            short8 pf[2], vf[4];
#pragma unroll
            for (int mt = 0; mt < 2; mt++)
                pf[mt] = *reinterpret_cast<const short8*>(
                    &Ps[(w * 32 + mt * 16 + c) * 72 + ks * 32 + q * 8]);
#pragma unroll
            for (int nt = 0; nt < 4; nt++)
                vf[nt] = *reinterpret_cast<const short8*>(&Vs[(nt * 16 + c) * 72 + ks * 32 + q * 8]);
#pragma unroll
            for (int mt = 0; mt < 2; mt++) {
#pragma unroll
                for (int nt = 0; nt < 4; nt++)
                    o_acc[mt][nt] = __builtin_amdgcn_mfma_f32_16x16x32_bf16(pf[mt], vf[nt], o_acc[mt][nt], 0, 0, 0);
                osum[mt] = __builtin_amdgcn_mfma_f32_16x16x32_bf16(pf[mt], v1, osum[mt], 0, 0, 0);
            }
        }

        if (chunk < 15) {
            __syncthreads();
#pragma unroll
            for (int i = 0; i < 2; i++) {
                int r = sr + i * 32;
                *reinterpret_cast<uint4v*>(&Ks[r * 72 + sc]) = kreg[i];
                *reinterpret_cast<uint4v*>(&Vs[r * 72 + sc]) = vreg[i];
            }
            __syncthreads();
        }
    }

#pragma unroll
    for (int mt = 0; mt < 2; mt++) {
        float inv[4];
#pragma unroll
        for (int r = 0; r < 4; r++) {
            float lv = __shfl(osum[mt][r], tid & 48);
            inv[r] = 1.0f / lv;
        }
#pragma unroll
        for (int nt = 0; nt < 4; nt++)
#pragma unroll
            for (int r = 0; r < 4; r++) {
                int row = qrow_base + mt * 16 + q * 4 + r;
                int col = (h << 6) + nt * 16 + c;
                ob[(size_t)row * 1024 + col] = f2b(o_acc[mt][nt][r] * inv[r]);
            }
    }
}

// ---------------------------------------------------------------------------
extern "C" void kernel_launch(void* const* d_in, const int* in_sizes, int n_in,
                              void* d_out, int out_size, void* d_ws, size_t ws_size,
                              hipStream_t stream) {
    const float* x    = (const float*)d_in[0];
    const float* wqkv = (const float*)d_in[1];
    const float* bqkv = (const float*)d_in[2];
    const float* wo   = (const float*)d_in[3];
    const float* bo   = (const float*)d_in[4];
    float* out = (float*)d_out;
    char* ws = (char*)d_ws;

    u16* xb    = (u16*)(ws);                 // [8192][1024]  16.8 MB
    u16* wqkvT = (u16*)(ws + 16777216);      // [3072][1024]   6.3 MB
    u16* woT   = (u16*)(ws + 23068672);      // [1024][1024]   2.1 MB
    u16* qkb   = (u16*)(ws + 25165824);      // [8192][2048]  33.6 MB
    u16* vtb   = (u16*)(ws + 58720256);      // [8192][1024]  16.8 MB (V^T per combo)
    u16* obuf  = (u16*)(ws + 75497472);      // [8192][1024]  16.8 MB
    // total 92.3 MB

    convert_x<<<8192, 256, 0, stream>>>(x, xb);
    transpose_convert<<<dim3(96, 32), dim3(32, 8), 0, stream>>>(wqkv, wqkvT, 1024, 3072);
    transpose_convert<<<dim3(32, 32), dim3(32, 8), 0, stream>>>(wo, woT, 1024, 1024);
    gemm_qkv256<<<dim3(12, 32), 512, 0, stream>>>(xb, wqkvT, bqkv,
                                                  qkb, vtb, 8192, 3072, 1024);
    attn<<<dim3(128, 8), 256, 0, stream>>>(qkb, vtb, obuf);
    gemm_bt<0><<<dim3(8, 64), 256, 0, stream>>>(obuf, woT, bo,
                                                out, nullptr, nullptr, 8192, 1024, 1024);
}